// Round 3
// baseline (433.473 us; speedup 1.0000x reference)
//
#include <hip/hip_runtime.h>
#include <math.h>

// ---------------- MS-SSIM on MI355X, round 3 ----------------
// Kernel A: level 0 (reads originals, writes pooled P1 pair + per-wave sums).
// Kernel B: levels 1-4 in ONE launch — each level's input is produced on the
// fly by locally avg-pooling P1 (pooling is block-local, mean-of-means=mean).
// Fully branchless row streaming: clamped loads * 0/1 masks, ds_bpermute with
// hoisted addresses, compile-time pool/vert flags (prologue + 10-row steady
// body + epilogue keeps parity static and code I$-resident).

static constexpr int TPB = 256;
static constexpr int TROWS = 32;

static constexpr int LVL_CNT[5] = {7680, 2304, 768, 192, 96};
static constexpr int LVL_OFF[5] = {0, 7680, 9984, 10752, 10944};

#define C1F 0.0001f
#define C2F 0.0009f
#define GW0f 0.12007838f
#define GW1f 0.23388060f
#define GW2f 0.29208204f

__device__ __forceinline__ float bperm(int addr, float v) {
    return __int_as_float(__builtin_amdgcn_ds_bpermute(addr, __float_as_int(v)));
}

// Load one level-row (2 level-cols per lane), pooling 2^k x 2^k blocks of the
// source when S>1. Branchless: clamped addresses, result scaled by mask.
template<int SRCW, int S>
__device__ __forceinline__ void load_row(const float* __restrict__ p1,
                                         const float* __restrict__ p2,
                                         int r, int c0c, float colm,
                                         float& x0, float& x1,
                                         float& z0, float& z1)
{
    constexpr int W = SRCW / S;              // level dims (W == H)
    const int rc = min(max(r, 0), W - 1);
    const float m = ((unsigned)r < (unsigned)W) ? colm : 0.f;
    if constexpr (S == 1) {
        const float2 a = *(const float2*)(p1 + (size_t)rc * SRCW + c0c);
        const float2 b = *(const float2*)(p2 + (size_t)rc * SRCW + c0c);
        x0 = a.x * m; x1 = a.y * m; z0 = b.x * m; z1 = b.y * m;
    } else {
        const float* r1 = p1 + (size_t)rc * S * SRCW + c0c * S;
        const float* r2 = p2 + (size_t)rc * S * SRCW + c0c * S;
        float s0 = 0.f, s1 = 0.f, t0 = 0.f, t1 = 0.f;
        #pragma unroll
        for (int j = 0; j < S; ++j) {
            const float* a = r1 + j * SRCW;
            const float* b = r2 + j * SRCW;
            if constexpr (S == 2) {
                const float4 A = *(const float4*)a;
                const float4 B = *(const float4*)b;
                s0 += A.x + A.y;  s1 += A.z + A.w;
                t0 += B.x + B.y;  t1 += B.z + B.w;
            } else if constexpr (S == 4) {
                const float4 A0 = *(const float4*)a;
                const float4 A1 = *(const float4*)(a + 4);
                const float4 B0 = *(const float4*)b;
                const float4 B1 = *(const float4*)(b + 4);
                s0 += (A0.x + A0.y) + (A0.z + A0.w);
                s1 += (A1.x + A1.y) + (A1.z + A1.w);
                t0 += (B0.x + B0.y) + (B0.z + B0.w);
                t1 += (B1.x + B1.y) + (B1.z + B1.w);
            } else { // S == 8
                const float4 A0 = *(const float4*)a;
                const float4 A1 = *(const float4*)(a + 4);
                const float4 A2 = *(const float4*)(a + 8);
                const float4 A3 = *(const float4*)(a + 12);
                const float4 B0 = *(const float4*)b;
                const float4 B1 = *(const float4*)(b + 4);
                const float4 B2 = *(const float4*)(b + 8);
                const float4 B3 = *(const float4*)(b + 12);
                s0 += ((A0.x + A0.y) + (A0.z + A0.w)) + ((A1.x + A1.y) + (A1.z + A1.w));
                s1 += ((A2.x + A2.y) + (A2.z + A2.w)) + ((A3.x + A3.y) + (A3.z + A3.w));
                t0 += ((B0.x + B0.y) + (B0.z + B0.w)) + ((B1.x + B1.y) + (B1.z + B1.w));
                t1 += ((B2.x + B2.y) + (B2.z + B2.w)) + ((B3.x + B3.y) + (B3.z + B3.w));
            }
        }
        constexpr float inv = 1.f / (float)(S * S);
        x0 = s0 * inv * m;  x1 = s1 * inv * m;
        z0 = t0 * inv * m;  z1 = t1 * inv * m;
    }
}

#define SSIM_ACC(A,B,Q,P) { \
    const float ab_   = (A)*(B); \
    const float a2b2_ = fmaf((A),(A),(B)*(B)); \
    const float s12_  = fmaf(2.f,(P)-ab_,C2F); \
    const float sden_ = ((Q)-a2b2_)+C2F; \
    const float d1_   = a2b2_+C1F; \
    const float n1_   = fmaf(2.f,ab_,C1F); \
    const float rd_   = __builtin_amdgcn_rcpf(d1_*sden_); \
    accs = fmaf(voutf, n1_*s12_*rd_, accs); \
    accc = fmaf(voutf, s12_*d1_*rd_, accc); }

// One row step. IEXPR = row index (runtime ok), J = IEXPR%5 (MUST be static),
// DO_PREF/DO_POOL_/DO_VERT are compile-time 0/1 flags.
#define ROW(IEXPR, J, DO_PREF, DO_POOL_, DO_VERT) { \
    constexpr int J_ = (J); \
    constexpr int K0=(J_+1)%5, K1=(J_+2)%5, K2=(J_+3)%5, K3=(J_+4)%5, K4=J_; \
    const int i_ = (IEXPR); \
    const float x0=nx0, x1=nx1, z0=nz0, z1=nz1; \
    if constexpr (DO_PREF) \
        load_row<SRCW,S>(p1, p2, y0 + i_ - 1, c0c, colm, nx0, nx1, nz0, nz1); \
    if constexpr (DO_POOL_ && POOL) { \
        if (voutf != 0.f) { \
            const int r_ = y0 + i_ - 2; \
            const size_t po_ = (size_t)(r_ >> 1) * (SRCW/2) + (c0 >> 1); \
            q1[po_] = (px0 + px1 + x0 + x1) * 0.25f; \
            q2[po_] = (py0 + py1 + z0 + z1) * 0.25f; \
        } } \
    if constexpr (POOL) { px0=x0; px1=x1; py0=z0; py1=z1; } \
    const float ux0=bperm(upA,x0), ux1=bperm(upA,x1); \
    const float dx0=bperm(dnA,x0), dx1=bperm(dnA,x1); \
    const float uz0=bperm(upA,z0), uz1=bperm(upA,z1); \
    const float dz0=bperm(dnA,z0), dz1=bperm(dnA,z1); \
    const float qu0=fmaf(ux0,ux0,uz0*uz0), qu1=fmaf(ux1,ux1,uz1*uz1); \
    const float qc0=fmaf(x0,x0,z0*z0),     qc1=fmaf(x1,x1,z1*z1); \
    const float qd0=fmaf(dx0,dx0,dz0*dz0), qd1=fmaf(dx1,dx1,dz1*dz1); \
    const float pu0=ux0*uz0, pu1=ux1*uz1; \
    const float pc0=x0*z0,   pc1=x1*z1; \
    const float pd0=dx0*dz0, pd1=dx1*dz1; \
    wa0[J_]=fmaf(GW0f,ux0+dx0,fmaf(GW1f,ux1+x1,GW2f*x0)); \
    wa1[J_]=fmaf(GW0f,ux1+dx1,fmaf(GW1f,x0+dx0,GW2f*x1)); \
    wb0[J_]=fmaf(GW0f,uz0+dz0,fmaf(GW1f,uz1+z1,GW2f*z0)); \
    wb1[J_]=fmaf(GW0f,uz1+dz1,fmaf(GW1f,z0+dz0,GW2f*z1)); \
    wq0[J_]=fmaf(GW0f,qu0+qd0,fmaf(GW1f,qu1+qc1,GW2f*qc0)); \
    wq1[J_]=fmaf(GW0f,qu1+qd1,fmaf(GW1f,qc0+qd0,GW2f*qc1)); \
    wp0[J_]=fmaf(GW0f,pu0+pd0,fmaf(GW1f,pu1+pc1,GW2f*pc0)); \
    wp1[J_]=fmaf(GW0f,pu1+pd1,fmaf(GW1f,pc0+pd0,GW2f*pc1)); \
    if constexpr (DO_VERT) { \
        const float A1_=fmaf(GW0f,wa0[K0]+wa0[K4],fmaf(GW1f,wa0[K1]+wa0[K3],GW2f*wa0[K2])); \
        const float B1_=fmaf(GW0f,wb0[K0]+wb0[K4],fmaf(GW1f,wb0[K1]+wb0[K3],GW2f*wb0[K2])); \
        const float Q1_=fmaf(GW0f,wq0[K0]+wq0[K4],fmaf(GW1f,wq0[K1]+wq0[K3],GW2f*wq0[K2])); \
        const float P1_=fmaf(GW0f,wp0[K0]+wp0[K4],fmaf(GW1f,wp0[K1]+wp0[K3],GW2f*wp0[K2])); \
        SSIM_ACC(A1_,B1_,Q1_,P1_); \
        const float A2_=fmaf(GW0f,wa1[K0]+wa1[K4],fmaf(GW1f,wa1[K1]+wa1[K3],GW2f*wa1[K2])); \
        const float B2_=fmaf(GW0f,wb1[K0]+wb1[K4],fmaf(GW1f,wb1[K1]+wb1[K3],GW2f*wb1[K2])); \
        const float Q2_=fmaf(GW0f,wq1[K0]+wq1[K4],fmaf(GW1f,wq1[K1]+wq1[K3],GW2f*wq1[K2])); \
        const float P2_=fmaf(GW0f,wp1[K0]+wp1[K4],fmaf(GW1f,wp1[K1]+wp1[K3],GW2f*wp1[K2])); \
        SSIM_ACC(A2_,B2_,Q2_,P2_); \
    } }

template<int SRCW, int S, bool POOL>
__device__ __forceinline__ void ssim_strip(const float* __restrict__ img1,
                                           const float* __restrict__ img2,
                                           const int w,
                                           float* __restrict__ pool1,
                                           float* __restrict__ pool2,
                                           double* __restrict__ wave_out)
{
    constexpr int W   = SRCW / S;            // level dims (W == H)
    constexpr int SX  = (W + 123) / 124;
    constexpr int SY  = (W >= TROWS) ? (W / TROWS) : 1;
    constexpr int SPP = SX * SY;

    const int lane  = threadIdx.x & 63;
    const int plane = w / SPP;
    const int rem   = w - plane * SPP;
    const int sy    = rem / SX;
    const int sx    = rem - sy * SX;

    const int y0  = sy * TROWS;
    const int c0  = sx * 124 - 2 + 2 * lane;
    const int c0c = min(max(c0, 0), W - 2);
    const float colm  = ((unsigned)c0 < (unsigned)W) ? 1.f : 0.f;
    const float voutf = (colm != 0.f && lane >= 1 && lane <= 62) ? 1.f : 0.f;
    const int upA = ((lane + 63) & 63) << 2;
    const int dnA = ((lane + 1) & 63) << 2;

    const float* p1 = img1 + (size_t)plane * SRCW * SRCW;
    const float* p2 = img2 + (size_t)plane * SRCW * SRCW;
    float* q1 = nullptr; float* q2 = nullptr;
    if constexpr (POOL) {
        q1 = pool1 + (size_t)plane * (SRCW/2) * (SRCW/2);
        q2 = pool2 + (size_t)plane * (SRCW/2) * (SRCW/2);
    }

    float wa0[5], wa1[5], wb0[5], wb1[5], wq0[5], wq1[5], wp0[5], wp1[5];
    float px0 = 0.f, px1 = 0.f, py0 = 0.f, py1 = 0.f;
    float accs = 0.f, accc = 0.f;
    float nx0, nx1, nz0, nz1;
    load_row<SRCW,S>(p1, p2, y0 - 2, c0c, colm, nx0, nx1, nz0, nz1);

    // prologue: rows 0..4 (first SSIM output at row idx 4; pool pair at 3)
    ROW(0, 0, 1, 0, 0)
    ROW(1, 1, 1, 0, 0)
    ROW(2, 2, 1, 0, 0)
    ROW(3, 3, 1, 1, 0)
    ROW(4, 4, 1, 0, 1)
    // steady: rows 5..34, 10-row body (odd i0 keeps pool-row parity static)
    #pragma unroll 1
    for (int i0 = 5; i0 <= 25; i0 += 10) {
        ROW(i0 + 0, 0, 1, 1, 1)
        ROW(i0 + 1, 1, 1, 0, 1)
        ROW(i0 + 2, 2, 1, 1, 1)
        ROW(i0 + 3, 3, 1, 0, 1)
        ROW(i0 + 4, 4, 1, 1, 1)
        ROW(i0 + 5, 0, 1, 0, 1)
        ROW(i0 + 6, 1, 1, 1, 1)
        ROW(i0 + 7, 2, 1, 0, 1)
        ROW(i0 + 8, 3, 1, 1, 1)
        ROW(i0 + 9, 4, 1, 0, 1)
    }
    // epilogue: row 35
    ROW(35, 0, 0, 0, 1)

    #pragma unroll
    for (int o = 32; o > 0; o >>= 1) {
        accs += __shfl_down(accs, o, 64);
        accc += __shfl_down(accc, o, 64);
    }
    if (lane == 0) {
        wave_out[0] = (double)accs;
        wave_out[1] = (double)accc;
    }
}

__global__ __launch_bounds__(TPB)
void ssim_l0_kernel(const float* __restrict__ img1,
                    const float* __restrict__ img2,
                    float* __restrict__ pool1,
                    float* __restrict__ pool2,
                    double* __restrict__ wsum)
{
    const int w = blockIdx.x * 4 + (threadIdx.x >> 6);
    ssim_strip<512, 1, true>(img1, img2, w, pool1, pool2, wsum + 2 * (size_t)w);
}

__global__ __launch_bounds__(TPB)
void ssim_rest_kernel(const float* __restrict__ P1a,
                      const float* __restrict__ P1b,
                      double* __restrict__ wsum)
{
    const int wv = threadIdx.x >> 6;
    const int b = blockIdx.x;
    if (b < 576) {                 // level 1: 2304 waves
        const int w = b * 4 + wv;
        ssim_strip<256, 1, false>(P1a, P1b, w, nullptr, nullptr,
                                  wsum + 2 * (size_t)(LVL_OFF[1] + w));
    } else if (b < 768) {          // level 2: 768 waves
        const int w = (b - 576) * 4 + wv;
        ssim_strip<256, 2, false>(P1a, P1b, w, nullptr, nullptr,
                                  wsum + 2 * (size_t)(LVL_OFF[2] + w));
    } else if (b < 816) {          // level 3: 192 waves
        const int w = (b - 768) * 4 + wv;
        ssim_strip<256, 4, false>(P1a, P1b, w, nullptr, nullptr,
                                  wsum + 2 * (size_t)(LVL_OFF[3] + w));
    } else {                       // level 4: 96 waves
        const int w = (b - 816) * 4 + wv;
        ssim_strip<256, 8, false>(P1a, P1b, w, nullptr, nullptr,
                                  wsum + 2 * (size_t)(LVL_OFF[4] + w));
    }
}

__global__ __launch_bounds__(256)
void ssim_final_kernel(const double* __restrict__ wsum, float* __restrict__ out)
{
    __shared__ double partial[4][2];
    __shared__ double lvl[5][2];
    const double npx[5] = {96.0*512*512, 96.0*256*256, 96.0*128*128,
                           96.0*64*64,   96.0*32*32};
    const int tid = threadIdx.x, lane = tid & 63, wv = tid >> 6;

    for (int l = 0; l < 5; ++l) {
        double s = 0.0, c = 0.0;
        for (int k = tid; k < LVL_CNT[l]; k += 256) {
            s += wsum[2 * (LVL_OFF[l] + k)];
            c += wsum[2 * (LVL_OFF[l] + k) + 1];
        }
        #pragma unroll
        for (int o = 32; o > 0; o >>= 1) {
            s += __shfl_down(s, o, 64);
            c += __shfl_down(c, o, 64);
        }
        if (lane == 0) { partial[wv][0] = s; partial[wv][1] = c; }
        __syncthreads();
        if (tid == 0) {
            double ts = partial[0][0] + partial[1][0] + partial[2][0] + partial[3][0];
            double tc = partial[0][1] + partial[1][1] + partial[2][1] + partial[3][1];
            lvl[l][0] = ts / npx[l];
            lvl[l][1] = tc / npx[l];
        }
        __syncthreads();
    }
    if (tid == 0) {
        const double w[5] = {0.0448, 0.2856, 0.3001, 0.2363, 0.1333};
        double ssim4 = (lvl[4][0] + 1.0) * 0.5;
        double P = pow(ssim4, w[4]);
        double r = pow((lvl[0][1] + 1.0) * 0.5, w[0]) *
                   pow((lvl[1][1] + 1.0) * 0.5, w[1]) *
                   pow((lvl[2][1] + 1.0) * 0.5, w[2]) *
                   pow((lvl[3][1] + 1.0) * 0.5, w[3]);
        r *= P * P * P * P;
        out[0] = (float)r;
    }
}

extern "C" void kernel_launch(void* const* d_in, const int* in_sizes, int n_in,
                              void* d_out, int out_size, void* d_ws, size_t ws_size,
                              hipStream_t stream)
{
    const float* img1 = (const float*)d_in[0];
    const float* img2 = (const float*)d_in[1];
    float* out = (float*)d_out;

    char* ws = (char*)d_ws;
    double* wsum = (double*)ws;                       // 11040 double2 (176 KB)
    float* l1a = (float*)(ws + 262144);               // P1 img1: 96*256*256
    float* l1b = l1a + (size_t)96 * 256 * 256;        // P1 img2

    ssim_l0_kernel  <<<LVL_CNT[0] / 4, TPB, 0, stream>>>(img1, img2, l1a, l1b, wsum);
    ssim_rest_kernel<<<840,            TPB, 0, stream>>>(l1a, l1b, wsum);
    ssim_final_kernel<<<1, 256, 0, stream>>>(wsum, out);
}

// Round 5
// 389.299 us; speedup vs baseline: 1.1135x; 1.1135x over previous
//
#include <hip/hip_runtime.h>
#include <math.h>

// ---------------- MS-SSIM on MI355X, round 5 ----------------
// Four regular launches (stream-ordered deps; cooperative launch failed in R4):
//   k_l0   : level0 from originals (W=512), writes pooled P1       1920 blocks
//   k_l1   : level1 from P1 (W=256), writes pooled P2               576 blocks
//   k_rest : levels 2/3/4 all from P2 (S=1/2/4 on-the-fly pooling)  264 blocks
//   k_final: reduce 11040 double2 partials + exact combination
// Strip engine: branchless clamp+mask loads, hoisted ds_bpermute addresses,
// prefetch-1 row, compile-time W/S/POOL, 36-row strips (TROWS=32).

static constexpr int TPB   = 256;
static constexpr int TROWS = 32;

static constexpr int LVL_CNT[5] = {7680, 2304, 768, 192, 96};
static constexpr int LVL_OFF[5] = {0, 7680, 9984, 10752, 10944};

#define C1F 0.0001f
#define C2F 0.0009f
#define GW0f 0.12007838f
#define GW1f 0.23388060f
#define GW2f 0.29208204f

__device__ __forceinline__ float bperm(int addr, float v) {
    return __int_as_float(__builtin_amdgcn_ds_bpermute(addr, __float_as_int(v)));
}

// Load one level-row (2 level-cols/lane). S>1: avg-pool SxS blocks of the
// (W*S)-wide source on the fly. Branchless: clamped row * 0/1 mask.
template<int W, int S>
__device__ __forceinline__ void load_row(const float* __restrict__ p1,
                                         const float* __restrict__ p2,
                                         int r, int c0c, float colm,
                                         float& x0, float& x1,
                                         float& z0, float& z1)
{
    constexpr int SRCW = W * S;
    const int rc = min(max(r, 0), W - 1);
    const float m = ((unsigned)r < (unsigned)W) ? colm : 0.f;
    if constexpr (S == 1) {
        const size_t o = (size_t)rc * W + c0c;
        const float2 a = *(const float2*)(p1 + o);
        const float2 b = *(const float2*)(p2 + o);
        x0 = a.x * m; x1 = a.y * m; z0 = b.x * m; z1 = b.y * m;
    } else {
        const float* a0 = p1 + (size_t)rc * S * SRCW + c0c * S;
        const float* b0 = p2 + (size_t)rc * S * SRCW + c0c * S;
        float s0 = 0.f, s1 = 0.f, t0 = 0.f, t1 = 0.f;
        #pragma unroll 1
        for (int j = 0; j < S; ++j) {
            const float* a = a0 + j * SRCW;
            const float* b = b0 + j * SRCW;
            if constexpr (S == 2) {
                const float4 A = *(const float4*)a;  s0 += A.x + A.y;  s1 += A.z + A.w;
                const float4 B = *(const float4*)b;  t0 += B.x + B.y;  t1 += B.z + B.w;
            } else { // S == 4
                const float4 A0 = *(const float4*)a;
                const float4 A1 = *(const float4*)(a + 4);
                s0 += (A0.x + A0.y) + (A0.z + A0.w);
                s1 += (A1.x + A1.y) + (A1.z + A1.w);
                const float4 B0 = *(const float4*)b;
                const float4 B1 = *(const float4*)(b + 4);
                t0 += (B0.x + B0.y) + (B0.z + B0.w);
                t1 += (B1.x + B1.y) + (B1.z + B1.w);
            }
        }
        constexpr float inv = 1.f / (float)(S * S);
        x0 = s0 * inv * m;  x1 = s1 * inv * m;
        z0 = t0 * inv * m;  z1 = t1 * inv * m;
    }
}

#define SSIM_ACC(A,B,Q,P) { \
    const float ab_   = (A)*(B); \
    const float a2b2_ = fmaf((A),(A),(B)*(B)); \
    const float s12_  = fmaf(2.f,(P)-ab_,C2F); \
    const float sden_ = ((Q)-a2b2_)+C2F; \
    const float d1_   = a2b2_+C1F; \
    const float n1_   = fmaf(2.f,ab_,C1F); \
    const float rd_   = __builtin_amdgcn_rcpf(d1_*sden_); \
    accs = fmaf(voutf, n1_*s12_*rd_, accs); \
    accc = fmaf(voutf, s12_*d1_*rd_, accc); }

// One row step. IEXPR = row index (runtime ok), J = IEXPR%5 (static),
// DO_PREF/DO_POOL_/DO_VERT compile-time. Prefetch distance 1 via nx regs.
#define ROW(IEXPR, J, DO_PREF, DO_POOL_, DO_VERT) { \
    constexpr int J_ = (J); \
    constexpr int K0=(J_+1)%5, K1=(J_+2)%5, K2=(J_+3)%5, K3=(J_+4)%5, K4=J_; \
    const int i_ = (IEXPR); \
    const float x0=nx0, x1=nx1, z0=nz0, z1=nz1; \
    if constexpr (DO_PREF) \
        load_row<W,S>(p1, p2, y0 + i_ - 1, c0c, colm, nx0, nx1, nz0, nz1); \
    if constexpr (DO_POOL_ && POOL) { \
        if (voutf != 0.f) { \
            const int r_ = y0 + i_ - 2; \
            const size_t po_ = (size_t)(r_ >> 1) * (W / 2) + (c0 >> 1); \
            q1[po_] = (px0 + px1 + x0 + x1) * 0.25f; \
            q2[po_] = (py0 + py1 + z0 + z1) * 0.25f; } } \
    if constexpr (POOL) { px0=x0; px1=x1; py0=z0; py1=z1; } \
    const float ux0=bperm(upA,x0), ux1=bperm(upA,x1); \
    const float dx0=bperm(dnA,x0), dx1=bperm(dnA,x1); \
    const float uz0=bperm(upA,z0), uz1=bperm(upA,z1); \
    const float dz0=bperm(dnA,z0), dz1=bperm(dnA,z1); \
    const float qu0=fmaf(ux0,ux0,uz0*uz0), qu1=fmaf(ux1,ux1,uz1*uz1); \
    const float qc0=fmaf(x0,x0,z0*z0),     qc1=fmaf(x1,x1,z1*z1); \
    const float qd0=fmaf(dx0,dx0,dz0*dz0), qd1=fmaf(dx1,dx1,dz1*dz1); \
    const float pu0=ux0*uz0, pu1=ux1*uz1; \
    const float pc0=x0*z0,   pc1=x1*z1; \
    const float pd0=dx0*dz0, pd1=dx1*dz1; \
    wa0[J_]=fmaf(GW0f,ux0+dx0,fmaf(GW1f,ux1+x1,GW2f*x0)); \
    wa1[J_]=fmaf(GW0f,ux1+dx1,fmaf(GW1f,x0+dx0,GW2f*x1)); \
    wb0[J_]=fmaf(GW0f,uz0+dz0,fmaf(GW1f,uz1+z1,GW2f*z0)); \
    wb1[J_]=fmaf(GW0f,uz1+dz1,fmaf(GW1f,z0+dz0,GW2f*z1)); \
    wq0[J_]=fmaf(GW0f,qu0+qd0,fmaf(GW1f,qu1+qc1,GW2f*qc0)); \
    wq1[J_]=fmaf(GW0f,qu1+qd1,fmaf(GW1f,qc0+qd0,GW2f*qc1)); \
    wp0[J_]=fmaf(GW0f,pu0+pd0,fmaf(GW1f,pu1+pc1,GW2f*pc0)); \
    wp1[J_]=fmaf(GW0f,pu1+pd1,fmaf(GW1f,pc0+pd0,GW2f*pc1)); \
    if constexpr (DO_VERT) { \
        const float A1_=fmaf(GW0f,wa0[K0]+wa0[K4],fmaf(GW1f,wa0[K1]+wa0[K3],GW2f*wa0[K2])); \
        const float B1_=fmaf(GW0f,wb0[K0]+wb0[K4],fmaf(GW1f,wb0[K1]+wb0[K3],GW2f*wb0[K2])); \
        const float Q1_=fmaf(GW0f,wq0[K0]+wq0[K4],fmaf(GW1f,wq0[K1]+wq0[K3],GW2f*wq0[K2])); \
        const float P1_=fmaf(GW0f,wp0[K0]+wp0[K4],fmaf(GW1f,wp0[K1]+wp0[K3],GW2f*wp0[K2])); \
        SSIM_ACC(A1_,B1_,Q1_,P1_); \
        const float A2_=fmaf(GW0f,wa1[K0]+wa1[K4],fmaf(GW1f,wa1[K1]+wa1[K3],GW2f*wa1[K2])); \
        const float B2_=fmaf(GW0f,wb1[K0]+wb1[K4],fmaf(GW1f,wb1[K1]+wb1[K3],GW2f*wb1[K2])); \
        const float Q2_=fmaf(GW0f,wq1[K0]+wq1[K4],fmaf(GW1f,wq1[K1]+wq1[K3],GW2f*wq1[K2])); \
        const float P2_=fmaf(GW0f,wp1[K0]+wp1[K4],fmaf(GW1f,wp1[K1]+wp1[K3],GW2f*wp1[K2])); \
        SSIM_ACC(A2_,B2_,Q2_,P2_); \
    } }

// One 124-col x 32-row strip of a WxW level whose input is the (W*S)-wide
// source pooled SxS. Writes one double2 partial; optionally pooled W/2 image.
template<int W, int S, bool POOL>
__device__ __forceinline__ void do_strip(const float* __restrict__ img1,
                                         const float* __restrict__ img2,
                                         int strip,
                                         float* __restrict__ pool1,
                                         float* __restrict__ pool2,
                                         double* __restrict__ out2)
{
    constexpr int SX  = (W + 123) / 124;
    constexpr int SY  = (W >= TROWS) ? (W / TROWS) : 1;
    constexpr int SPP = SX * SY;
    constexpr int SRCW = W * S;

    const int lane  = threadIdx.x & 63;
    const int plane = strip / SPP;
    const int rem   = strip - plane * SPP;
    const int sy    = rem / SX;
    const int sx    = rem - sy * SX;
    const int y0  = sy * TROWS;
    const int c0  = sx * 124 - 2 + 2 * lane;
    const int c0c = min(max(c0, 0), W - 2);
    const float colm  = ((unsigned)c0 < (unsigned)W) ? 1.f : 0.f;
    const float voutf = (colm != 0.f && lane >= 1 && lane <= 62) ? 1.f : 0.f;
    const int upA = ((lane + 63) & 63) << 2;
    const int dnA = ((lane + 1) & 63) << 2;

    const float* p1 = img1 + (size_t)plane * SRCW * SRCW;
    const float* p2 = img2 + (size_t)plane * SRCW * SRCW;
    float* q1 = nullptr; float* q2 = nullptr;
    if constexpr (POOL) {
        q1 = pool1 + (size_t)plane * (W / 2) * (W / 2);
        q2 = pool2 + (size_t)plane * (W / 2) * (W / 2);
    }

    float wa0[5], wa1[5], wb0[5], wb1[5], wq0[5], wq1[5], wp0[5], wp1[5];
    float px0 = 0.f, px1 = 0.f, py0 = 0.f, py1 = 0.f;
    float accs = 0.f, accc = 0.f;
    float nx0, nx1, nz0, nz1;
    load_row<W,S>(p1, p2, y0 - 2, c0c, colm, nx0, nx1, nz0, nz1);

    // prologue rows 0..4 (first SSIM out at i=4; first pool pair at i=3)
    ROW(0, 0, 1, 0, 0)
    ROW(1, 1, 1, 0, 0)
    ROW(2, 2, 1, 0, 0)
    ROW(3, 3, 1, 1, 0)
    ROW(4, 4, 1, 0, 1)
    // steady rows 5..34: 10-row body keeps J and pool parity static
    #pragma unroll 1
    for (int i0 = 5; i0 <= 25; i0 += 10) {
        ROW(i0 + 0, 0, 1, 1, 1)
        ROW(i0 + 1, 1, 1, 0, 1)
        ROW(i0 + 2, 2, 1, 1, 1)
        ROW(i0 + 3, 3, 1, 0, 1)
        ROW(i0 + 4, 4, 1, 1, 1)
        ROW(i0 + 5, 0, 1, 0, 1)
        ROW(i0 + 6, 1, 1, 1, 1)
        ROW(i0 + 7, 2, 1, 0, 1)
        ROW(i0 + 8, 3, 1, 1, 1)
        ROW(i0 + 9, 4, 1, 0, 1)
    }
    // epilogue row 35 (no prefetch, no pool)
    ROW(35, 0, 0, 0, 1)

    #pragma unroll
    for (int o = 32; o > 0; o >>= 1) {
        accs += __shfl_down(accs, o, 64);
        accc += __shfl_down(accc, o, 64);
    }
    if (lane == 0) { out2[0] = (double)accs; out2[1] = (double)accc; }
}

__global__ __launch_bounds__(TPB)
void k_l0(const float* __restrict__ img1, const float* __restrict__ img2,
          float* __restrict__ P1a, float* __restrict__ P1b,
          double* __restrict__ wsum)
{
    const int strip = blockIdx.x * 4 + (threadIdx.x >> 6);
    do_strip<512, 1, true>(img1, img2, strip, P1a, P1b, wsum + 2 * (size_t)strip);
}

__global__ __launch_bounds__(TPB)
void k_l1(const float* __restrict__ P1a, const float* __restrict__ P1b,
          float* __restrict__ P2a, float* __restrict__ P2b,
          double* __restrict__ wsum)
{
    const int strip = blockIdx.x * 4 + (threadIdx.x >> 6);
    do_strip<256, 1, true>(P1a, P1b, strip, P2a, P2b,
                           wsum + 2 * (size_t)(LVL_OFF[1] + strip));
}

__global__ __launch_bounds__(TPB)
void k_rest(const float* __restrict__ P2a, const float* __restrict__ P2b,
            double* __restrict__ wsum)
{
    const int wv = threadIdx.x >> 6;
    const int b = blockIdx.x;
    if (b < 192) {               // level 2: 768 strips, W=128 direct
        const int s = b * 4 + wv;
        do_strip<128, 1, false>(P2a, P2b, s, nullptr, nullptr,
                                wsum + 2 * (size_t)(LVL_OFF[2] + s));
    } else if (b < 240) {        // level 3: 192 strips, W=64, pool 2x2
        const int s = (b - 192) * 4 + wv;
        do_strip<64, 2, false>(P2a, P2b, s, nullptr, nullptr,
                               wsum + 2 * (size_t)(LVL_OFF[3] + s));
    } else {                     // level 4: 96 strips, W=32, pool 4x4
        const int s = (b - 240) * 4 + wv;
        do_strip<32, 4, false>(P2a, P2b, s, nullptr, nullptr,
                               wsum + 2 * (size_t)(LVL_OFF[4] + s));
    }
}

__global__ __launch_bounds__(256)
void k_final(const double* __restrict__ wsum, float* __restrict__ out)
{
    __shared__ double partial[4][2];
    __shared__ double lvl[5][2];
    const double npx[5] = {96.0*512*512, 96.0*256*256, 96.0*128*128,
                           96.0*64*64,   96.0*32*32};
    const int tid = threadIdx.x, lane = tid & 63, wv = tid >> 6;

    for (int l = 0; l < 5; ++l) {
        double s = 0.0, c = 0.0;
        for (int k = tid; k < LVL_CNT[l]; k += 256) {
            s += wsum[2 * (size_t)(LVL_OFF[l] + k)];
            c += wsum[2 * (size_t)(LVL_OFF[l] + k) + 1];
        }
        #pragma unroll
        for (int o = 32; o > 0; o >>= 1) {
            s += __shfl_down(s, o, 64);
            c += __shfl_down(c, o, 64);
        }
        if (lane == 0) { partial[wv][0] = s; partial[wv][1] = c; }
        __syncthreads();
        if (tid == 0) {
            lvl[l][0] = (partial[0][0]+partial[1][0]+partial[2][0]+partial[3][0]) / npx[l];
            lvl[l][1] = (partial[0][1]+partial[1][1]+partial[2][1]+partial[3][1]) / npx[l];
        }
        __syncthreads();
    }
    if (tid == 0) {
        const double w[5] = {0.0448, 0.2856, 0.3001, 0.2363, 0.1333};
        double ssim4 = (lvl[4][0] + 1.0) * 0.5;
        double P = pow(ssim4, w[4]);
        double r = pow((lvl[0][1] + 1.0) * 0.5, w[0]) *
                   pow((lvl[1][1] + 1.0) * 0.5, w[1]) *
                   pow((lvl[2][1] + 1.0) * 0.5, w[2]) *
                   pow((lvl[3][1] + 1.0) * 0.5, w[3]);
        r *= P * P * P * P;
        out[0] = (float)r;
    }
}

extern "C" void kernel_launch(void* const* d_in, const int* in_sizes, int n_in,
                              void* d_out, int out_size, void* d_ws, size_t ws_size,
                              hipStream_t stream)
{
    const float* img1 = (const float*)d_in[0];
    const float* img2 = (const float*)d_in[1];
    float* out = (float*)d_out;

    char* ws = (char*)d_ws;
    double* wsum = (double*)ws;                 // 11040 double2 = 176.6 KB
    float* P1a = (float*)(ws + 262144);         // 96*256*256 floats each
    float* P1b = P1a + (size_t)96 * 256 * 256;
    float* P2a = P1b + (size_t)96 * 256 * 256;  // 96*128*128 floats each
    float* P2b = P2a + (size_t)96 * 128 * 128;

    k_l0  <<<LVL_CNT[0] / 4, TPB, 0, stream>>>(img1, img2, P1a, P1b, wsum);
    k_l1  <<<LVL_CNT[1] / 4, TPB, 0, stream>>>(P1a, P1b, P2a, P2b, wsum);
    k_rest<<<264,            TPB, 0, stream>>>(P2a, P2b, wsum);
    k_final<<<1, 256, 0, stream>>>(wsum, out);
}